// Round 10
// baseline (206.932 us; speedup 1.0000x reference)
//
#include <hip/hip_runtime.h>

#define NCH 80
#define HW 16384

typedef unsigned short u16;
typedef unsigned int u32;
typedef short s16x8 __attribute__((ext_vector_type(8)));
typedef float f32x4 __attribute__((ext_vector_type(4)));

__device__ __forceinline__ float b2f_lo(u32 pk){ union{u32 u; float f;} c; c.u = pk<<16; return c.f; }
__device__ __forceinline__ float b2f_hi(u32 pk){ union{u32 u; float f;} c; c.u = pk & 0xffff0000u; return c.f; }
__device__ __forceinline__ u16 f2b_hw(float f){
    union{ __bf16 h; u16 s; } c; c.h = (__bf16)f; return c.s;
}
__device__ __forceinline__ u32 pk2(float a, float b){
    return (u32)f2b_hw(a) | ((u32)f2b_hw(b)<<16);
}
#define NEG_INF (-__builtin_inff())

union U4S8 { uint4 u; s16x8 v; };

// ---------------------------------------------------------------- P0: weight pack -> bf16
__global__ __launch_bounds__(256) void k_wcvt(
    const float* __restrict__ qw, const float* __restrict__ qb,
    const float* __restrict__ kw, const float* __restrict__ kb,
    const float* __restrict__ vw, const float* __restrict__ vb,
    u16* __restrict__ wbf, float* __restrict__ bias80)
{
    int i = blockIdx.x*256 + threadIdx.x;     // 0..10239
    int ch = i >> 7, cin = i & 127;
    float v;
    if (ch < 8)       v = (cin < 64) ? qw[ch*64 + cin] : 0.f;
    else if (ch < 16) v = (cin >= 64) ? kw[(ch-8)*64 + (cin-64)] : 0.f;
    else              v = vw[(ch-16)*128 + cin];
    wbf[i] = f2b_hw(v);
    if (i < 80){
        bias80[i] = (i<8) ? qb[i] : (i<16) ? kb[i-8] : vb[i-16];
    }
}

// ---------------------------------------------------------------- P1: qkv via MFMA (R6 structure, best measured: 69us)
// Block = 256 thr (4 waves), 128 pixels. Phase A: 16 float4 loads, then
// convert -> LDS [cp][px] + fused xy emit. Phase B: MFMA vs L1-resident weights.
__global__ __launch_bounds__(256) void k_qkv_mfma(
    const float* __restrict__ x, const float* __restrict__ y,
    const u16* __restrict__ wbf, const float* __restrict__ bias80,
    u16* __restrict__ qkv, u16* __restrict__ xy)
{
    // a32[cp][px]: cp<32 -> x channel-pair (2cp,2cp+1); cp>=32 -> y channel-pair.
    __shared__ u32 a32[64*132];

    int t = threadIdx.x;
    int p0 = blockIdx.x * 128;
    int b = p0 >> 14, rem = p0 & 16383;
    const float* xb = x + (size_t)b*64*HW + rem;
    const float* yb = y + (size_t)b*64*HW + rem;

    // ---- Phase A1: issue ALL 16 loads (no LDS dependency in between)
    float4 fx0[4], fx1[4], fy0[4], fy1[4];
    #pragma unroll
    for (int r=0;r<4;r++){
        int idx = t + r*256;              // 0..1023
        int cp = idx >> 5;                // 0..31 channel-pair
        int pxg = (idx & 31) * 4;         // pixel group base
        const float* xp = xb + (size_t)(2*cp)*HW + pxg;
        const float* yp = yb + (size_t)(2*cp)*HW + pxg;
        fx0[r] = *(const float4*)xp;
        fx1[r] = *(const float4*)(xp + HW);
        fy0[r] = *(const float4*)yp;
        fy1[r] = *(const float4*)(yp + HW);
    }
    // ---- Phase A2: convert + LDS + fused xy emit
    #pragma unroll
    for (int r=0;r<4;r++){
        int idx = t + r*256;
        int cp = idx >> 5;
        int pxg = (idx & 31) * 4;
        uint4 wx, wy;
        wx.x = pk2(fx0[r].x, fx1[r].x);
        wx.y = pk2(fx0[r].y, fx1[r].y);
        wx.z = pk2(fx0[r].z, fx1[r].z);
        wx.w = pk2(fx0[r].w, fx1[r].w);
        wy.x = pk2(fy0[r].x, fy1[r].x);
        wy.y = pk2(fy0[r].y, fy1[r].y);
        wy.z = pk2(fy0[r].z, fy1[r].z);
        wy.w = pk2(fy0[r].w, fy1[r].w);
        *(uint4*)&a32[cp*132 + pxg]       = wx;
        *(uint4*)&a32[(32+cp)*132 + pxg]  = wy;
        if (xy){
            uint2 s0, s1;
            s0.x = pk2(fx0[r].x+fy0[r].x, fx0[r].y+fy0[r].y);
            s0.y = pk2(fx0[r].z+fy0[r].z, fx0[r].w+fy0[r].w);
            s1.x = pk2(fx1[r].x+fy1[r].x, fx1[r].y+fy1[r].y);
            s1.y = pk2(fx1[r].z+fy1[r].z, fx1[r].w+fy1[r].w);
            *(uint2*)&xy[(size_t)(b*64 + 2*cp)*HW + rem + pxg]     = s0;
            *(uint2*)&xy[(size_t)(b*64 + 2*cp+1)*HW + rem + pxg]   = s1;
        }
    }
    __syncthreads();

    // ---- Phase B: MFMA. Wave wv owns pixels [(2wv)*16, (2wv+2)*16), 5 n-tiles.
    int wv = t >> 6, l = t & 63;
    int lm = l & 15, lq = l >> 4;

    s16x8 af[2][4];
    #pragma unroll
    for (int m2=0;m2<2;m2++){
        int pxl = (wv*2 + m2)*16 + lm;
        #pragma unroll
        for (int ks=0;ks<4;ks++){
            int cpb = (ks&1)*16 + lq*4 + ((ks>>1)*32);
            U4S8 uu;
            uu.u = make_uint4(a32[(cpb+0)*132 + pxl], a32[(cpb+1)*132 + pxl],
                              a32[(cpb+2)*132 + pxl], a32[(cpb+3)*132 + pxl]);
            af[m2][ks] = uu.v;
        }
    }

    #pragma unroll
    for (int nt=0;nt<5;nt++){
        int ch = nt*16 + lm;
        const u16* wrow = wbf + ch*128 + lq*8;
        s16x8 b0 = *(const s16x8*)(wrow);
        s16x8 b1 = *(const s16x8*)(wrow + 32);
        s16x8 b2 = *(const s16x8*)(wrow + 64);
        s16x8 b3 = *(const s16x8*)(wrow + 96);
        f32x4 acc0 = (f32x4){0.f,0.f,0.f,0.f};
        f32x4 acc1 = (f32x4){0.f,0.f,0.f,0.f};
        acc0 = __builtin_amdgcn_mfma_f32_16x16x32_bf16(af[0][0], b0, acc0, 0,0,0);
        acc1 = __builtin_amdgcn_mfma_f32_16x16x32_bf16(af[1][0], b0, acc1, 0,0,0);
        acc0 = __builtin_amdgcn_mfma_f32_16x16x32_bf16(af[0][1], b1, acc0, 0,0,0);
        acc1 = __builtin_amdgcn_mfma_f32_16x16x32_bf16(af[1][1], b1, acc1, 0,0,0);
        acc0 = __builtin_amdgcn_mfma_f32_16x16x32_bf16(af[0][2], b2, acc0, 0,0,0);
        acc1 = __builtin_amdgcn_mfma_f32_16x16x32_bf16(af[1][2], b2, acc1, 0,0,0);
        acc0 = __builtin_amdgcn_mfma_f32_16x16x32_bf16(af[0][3], b3, acc0, 0,0,0);
        acc1 = __builtin_amdgcn_mfma_f32_16x16x32_bf16(af[1][3], b3, acc1, 0,0,0);
        float bs = bias80[ch];
        size_t chbase = (size_t)(b*NCH + ch)*HW + rem;
        uint2 st0, st1;
        st0.x = pk2(acc0[0]+bs, acc0[1]+bs);
        st0.y = pk2(acc0[2]+bs, acc0[3]+bs);
        st1.x = pk2(acc1[0]+bs, acc1[1]+bs);
        st1.y = pk2(acc1[2]+bs, acc1[3]+bs);
        *(uint2*)&qkv[chbase + (wv*2+0)*16 + lq*4] = st0;
        *(uint2*)&qkv[chbase + (wv*2+1)*16 + lq*4] = st1;
    }
}

// ------------------------------------------------ 128x128 bf16 plane transpose
__global__ __launch_bounds__(256) void k_tr(const u16* __restrict__ src, u16* __restrict__ dst)
{
    __shared__ u16 tile[64][65];
    int blk = blockIdx.x;
    int plane = blk >> 2, tq = blk & 3;
    int r0 = (tq >> 1) * 64, c0 = (tq & 1) * 64;
    const u16* s = src + (size_t)plane * HW;
    u16* d = dst + (size_t)plane * HW;
    int col = threadIdx.x & 63, rr = threadIdx.x >> 6;
    #pragma unroll
    for (int k=0;k<16;k++){
        int r = k*4 + rr;
        tile[r][col] = s[(r0+r)*128 + c0 + col];
    }
    __syncthreads();
    #pragma unroll
    for (int k=0;k<16;k++){
        int r = k*4 + rr;
        d[(c0+r)*128 + r0 + col] = tile[col][r];
    }
}

// ---------------------------------------------------------------- P2: column pass (MFMA PV)
// Writes colpart in NATURAL [c][h][w] layout via u16 scatter (L2 write-combined:
// XCD-aware swizzle puts each (b, w-group-of-32) chunk on one XCD).
__global__ __launch_bounds__(512, 4) void k_col(
    const u16* __restrict__ qkvT, u16* __restrict__ colp,
    float* __restrict__ mH, float* __restrict__ sH)
{
    __shared__ __align__(16) float q_s[8*128];    // [o][h]
    __shared__ __align__(16) float k_sw[8*128];   // [g][o^((g>>3)&7)]
    __shared__ __align__(16) u16  v_bf[64*128];   // [c][g], word ^ ((c&7)<<2)
    __shared__ __align__(16) u16  p_bf[128*128];  // [h][g], word ^ ((h&7)<<2)

    int t = threadIdx.x;
    // ---- bijective XCD-aware decode: blocks sharing colpart 64B lines -> same XCD
    int i = blockIdx.x;                 // 0..2047
    int xcd = i & 7, n = i >> 3;        // n: 0..255 within xcd
    int chunk = (n >> 5)*8 + xcd;       // 0..63 = b*4 + (w>>5)
    int b = chunk >> 2;
    int w = ((chunk & 3) << 5) + (n & 31);

    const u32* src = (const u32*)(qkvT + (size_t)b*NCH*HW + w*128);
    u32* v32 = (u32*)v_bf;
    u32* p32 = (u32*)p_bf;

    #pragma unroll
    for (int r=0;r<2;r++){
        int idx = t + r*512;
        int ch = idx >> 6, hp = idx & 63;
        u32 pk = src[ch*8192 + hp];
        int g0 = hp*2;
        if (ch < 8){
            *(float2*)&q_s[ch*128 + g0] = make_float2(b2f_lo(pk), b2f_hi(pk));
        } else {
            int o = ch - 8;
            k_sw[g0*8     + (o ^ ((g0>>3)&7))]     = b2f_lo(pk);
            k_sw[(g0+1)*8 + (o ^ (((g0+1)>>3)&7))] = b2f_hi(pk);
        }
    }
    #pragma unroll
    for (int r=0;r<8;r++){
        int idx = t + r*512;
        int c = idx >> 6, gp = idx & 63;
        v32[(c*64 + gp) ^ ((c&7)<<2)] = src[(16+c)*8192 + gp];
    }
    __syncthreads();

    int tr = t >> 4, tc = t & 15;
    int h0 = tr*4, g0 = tc*8;
    float e[4][8];
    #pragma unroll
    for (int i2=0;i2<4;i2++)
        #pragma unroll
        for (int j=0;j<8;j++) e[i2][j] = 0.f;

    #pragma unroll
    for (int o=0;o<8;o++){
        float qv[4], kv[8];
        #pragma unroll
        for (int i2=0;i2<4;i2++) qv[i2] = q_s[o*128 + h0 + i2];
        int kb = o ^ (tc & 7);
        #pragma unroll
        for (int j=0;j<8;j++) kv[j] = k_sw[(g0+j)*8 + kb];
        #pragma unroll
        for (int i2=0;i2<4;i2++)
            #pragma unroll
            for (int j=0;j<8;j++) e[i2][j] += qv[i2]*kv[j];
    }
    #pragma unroll
    for (int i2=0;i2<4;i2++){
        int h = h0 + i2;
        if ((h>>3) == tc) e[i2][h&7] = NEG_INF;
    }
    #pragma unroll
    for (int i2=0;i2<4;i2++){
        int h = h0 + i2;
        float m = e[i2][0];
        #pragma unroll
        for (int j=1;j<8;j++) m = fmaxf(m, e[i2][j]);
        m = fmaxf(m, __shfl_xor(m,1));
        m = fmaxf(m, __shfl_xor(m,2));
        m = fmaxf(m, __shfl_xor(m,4));
        m = fmaxf(m, __shfl_xor(m,8));
        float s = 0.f;
        #pragma unroll
        for (int j=0;j<8;j++){ float pp = __expf(e[i2][j]-m); e[i2][j]=pp; s += pp; }
        s += __shfl_xor(s,1);
        s += __shfl_xor(s,2);
        s += __shfl_xor(s,4);
        s += __shfl_xor(s,8);
        if (tc == 0){
            mH[b*HW + h*128 + w] = m;
            sH[b*HW + h*128 + w] = s;
        }
        uint4 pw;
        pw.x = pk2(e[i2][0], e[i2][1]);
        pw.y = pk2(e[i2][2], e[i2][3]);
        pw.z = pk2(e[i2][4], e[i2][5]);
        pw.w = pk2(e[i2][6], e[i2][7]);
        *(uint4*)&p32[(h*64 + tc*4) ^ ((h&7)<<2)] = pw;
    }
    __syncthreads();

    int wv = t >> 6, l = t & 63;
    int lm = l & 15, lq = l >> 4;
    int mt = wv;
    f32x4 acc[4];
    #pragma unroll
    for (int nt=0; nt<4; nt++) acc[nt] = (f32x4){0.f,0.f,0.f,0.f};

    #pragma unroll
    for (int ks=0; ks<4; ks++){
        int ri = mt*16 + lm;
        s16x8 a = *(const s16x8*)&p32[(ri*64 + ks*16 + lq*4) ^ ((ri&7)<<2)];
        #pragma unroll
        for (int nt=0; nt<4; nt++){
            int c = nt*16 + lm;
            s16x8 bf_ = *(const s16x8*)&v32[(c*64 + ks*16 + lq*4) ^ ((c&7)<<2)];
            acc[nt] = __builtin_amdgcn_mfma_f32_16x16x32_bf16(a, bf_, acc[nt], 0, 0, 0);
        }
    }
    // ---- natural-layout scatter stores: colp[c][h][w], 2B each, L2-combined
    #pragma unroll
    for (int nt=0; nt<4; nt++){
        int c = nt*16 + lm;
        size_t base = (size_t)(b*64+c)*HW + w;
        int hh = mt*16 + lq*4;
        colp[base + (size_t)(hh+0)*128] = f2b_hw(acc[nt][0]);
        colp[base + (size_t)(hh+1)*128] = f2b_hw(acc[nt][1]);
        colp[base + (size_t)(hh+2)*128] = f2b_hw(acc[nt][2]);
        colp[base + (size_t)(hh+3)*128] = f2b_hw(acc[nt][3]);
    }
}

// ---------------------------------------------------------------- P3: row pass + combine (MFMA PV)
__global__ __launch_bounds__(512, 4) void k_row(
    const u16* __restrict__ qkv, const u16* __restrict__ colpart,
    const float* __restrict__ mH, const float* __restrict__ sH,
    const float* __restrict__ x, const float* __restrict__ y,
    const u16* __restrict__ xy,
    const float* __restrict__ gamma_p, float* __restrict__ out)
{
    __shared__ __align__(16) float q_s[8*128];
    __shared__ __align__(16) float k_sw[8*128];
    __shared__ __align__(16) u16  v_bf[64*128];
    __shared__ __align__(16) u16  p_bf[128*128];
    __shared__ float fc_s[128], fr_s[128];

    int t = threadIdx.x;
    int b = blockIdx.x >> 7, h = blockIdx.x & 127;
    const u32* src = (const u32*)(qkv + (size_t)b*NCH*HW + h*128);
    u32* v32 = (u32*)v_bf;
    u32* p32 = (u32*)p_bf;

    #pragma unroll
    for (int r=0;r<2;r++){
        int idx = t + r*512;
        int ch = idx >> 6, wp = idx & 63;
        u32 pk = src[ch*8192 + wp];
        int u0 = wp*2;
        if (ch < 8){
            *(float2*)&q_s[ch*128 + u0] = make_float2(b2f_lo(pk), b2f_hi(pk));
        } else {
            int o = ch - 8;
            k_sw[u0*8     + (o ^ ((u0>>3)&7))]     = b2f_lo(pk);
            k_sw[(u0+1)*8 + (o ^ (((u0+1)>>3)&7))] = b2f_hi(pk);
        }
    }
    #pragma unroll
    for (int r=0;r<8;r++){
        int idx = t + r*512;
        int c = idx >> 6, up = idx & 63;
        v32[(c*64 + up) ^ ((c&7)<<2)] = src[(16+c)*8192 + up];
    }
    __syncthreads();

    int tr = t >> 4, tc = t & 15;
    int w0 = tr*4, u0 = tc*8;
    float e[4][8];
    #pragma unroll
    for (int i=0;i<4;i++)
        #pragma unroll
        for (int j=0;j<8;j++) e[i][j] = 0.f;

    #pragma unroll
    for (int o=0;o<8;o++){
        float qv[4], kv[8];
        #pragma unroll
        for (int i=0;i<4;i++) qv[i] = q_s[o*128 + w0 + i];
        int kb = o ^ (tc & 7);
        #pragma unroll
        for (int j=0;j<8;j++) kv[j] = k_sw[(u0+j)*8 + kb];
        #pragma unroll
        for (int i=0;i<4;i++)
            #pragma unroll
            for (int j=0;j<8;j++) e[i][j] += qv[i]*kv[j];
    }
    int pixbase = b*HW + h*128;
    #pragma unroll
    for (int i=0;i<4;i++){
        int wp = w0 + i;
        float m = e[i][0];
        #pragma unroll
        for (int j=1;j<8;j++) m = fmaxf(m, e[i][j]);
        m = fmaxf(m, __shfl_xor(m,1));
        m = fmaxf(m, __shfl_xor(m,2));
        m = fmaxf(m, __shfl_xor(m,4));
        m = fmaxf(m, __shfl_xor(m,8));
        float mh = mH[pixbase + wp];
        float sh = sH[pixbase + wp];
        float mg = fmaxf(m, mh);
        float s = 0.f;
        #pragma unroll
        for (int j=0;j<8;j++){ float pp = __expf(e[i][j]-mg); e[i][j]=pp; s += pp; }
        s += __shfl_xor(s,1);
        s += __shfl_xor(s,2);
        s += __shfl_xor(s,4);
        s += __shfl_xor(s,8);
        if (tc == 0){
            float ef = __expf(mh - mg);
            float stot = sh*ef + s;
            fc_s[wp] = ef/stot;
            fr_s[wp] = 1.0f/stot;
        }
        uint4 pw;
        pw.x = pk2(e[i][0], e[i][1]);
        pw.y = pk2(e[i][2], e[i][3]);
        pw.z = pk2(e[i][4], e[i][5]);
        pw.w = pk2(e[i][6], e[i][7]);
        *(uint4*)&p32[(wp*64 + tc*4) ^ ((wp&7)<<2)] = pw;
    }
    __syncthreads();

    int wv = t >> 6, l = t & 63;
    int lm = l & 15, lq = l >> 4;
    int mt = wv;
    f32x4 acc[4];
    #pragma unroll
    for (int nt=0; nt<4; nt++) acc[nt] = (f32x4){0.f,0.f,0.f,0.f};

    #pragma unroll
    for (int ks=0; ks<4; ks++){
        int ri = mt*16 + lm;
        s16x8 a = *(const s16x8*)&p32[(ri*64 + ks*16 + lq*4) ^ ((ri&7)<<2)];
        #pragma unroll
        for (int nt=0; nt<4; nt++){
            int c = nt*16 + lm;
            s16x8 bf_ = *(const s16x8*)&v32[(c*64 + ks*16 + lq*4) ^ ((c&7)<<2)];
            acc[nt] = __builtin_amdgcn_mfma_f32_16x16x32_bf16(a, bf_, acc[nt], 0, 0, 0);
        }
    }
    float gm = gamma_p[0];
    int wq0 = mt*16 + lq*4;
    float fcv[4], frv[4];
    #pragma unroll
    for (int r2=0;r2<4;r2++){ fcv[r2] = fc_s[wq0+r2]; frv[r2] = fr_s[wq0+r2]; }

    #pragma unroll
    for (int nt=0; nt<4; nt++){
        int c = nt*16 + lm;
        size_t off = ((size_t)(b*64+c)*128 + h)*128 + wq0;
        uint2 cpv = *(const uint2*)&colpart[off];
        float cp[4] = {b2f_lo(cpv.x), b2f_hi(cpv.x), b2f_lo(cpv.y), b2f_hi(cpv.y)};
        float xs[4];
        if (xy){
            uint2 xv = *(const uint2*)&xy[off];
            xs[0]=b2f_lo(xv.x); xs[1]=b2f_hi(xv.x); xs[2]=b2f_lo(xv.y); xs[3]=b2f_hi(xv.y);
        } else {
            float4 x4 = *(const float4*)&x[off];
            float4 y4 = *(const float4*)&y[off];
            xs[0]=x4.x+y4.x; xs[1]=x4.y+y4.y; xs[2]=x4.z+y4.z; xs[3]=x4.w+y4.w;
        }
        float4 o4;
        o4.x = gm*(cp[0]*fcv[0] + acc[nt][0]*frv[0]) + xs[0];
        o4.y = gm*(cp[1]*fcv[1] + acc[nt][1]*frv[1]) + xs[1];
        o4.z = gm*(cp[2]*fcv[2] + acc[nt][2]*frv[2]) + xs[2];
        o4.w = gm*(cp[3]*fcv[3] + acc[nt][3]*frv[3]) + xs[3];
        *(float4*)&out[off] = o4;
    }
}

// ----------------------------------------------------------------
extern "C" void kernel_launch(void* const* d_in, const int* in_sizes, int n_in,
                              void* d_out, int out_size, void* d_ws, size_t ws_size,
                              hipStream_t stream)
{
    (void)in_sizes; (void)n_in; (void)out_size;
    const float* x  = (const float*)d_in[0];
    const float* y  = (const float*)d_in[1];
    const float* qw = (const float*)d_in[2];
    const float* qb = (const float*)d_in[3];
    const float* kw = (const float*)d_in[4];
    const float* kb = (const float*)d_in[5];
    const float* vw = (const float*)d_in[6];
    const float* vb = (const float*)d_in[7];
    const float* gm = (const float*)d_in[8];
    float* out = (float*)d_out;

    char* ws = (char*)d_ws;
    u16* qkv     = (u16*)(ws);                    // 41,943,040 B
    u16* qkvT    = (u16*)(ws + 41943040ull);      // 41,943,040 B
    u16* colpart = (u16*)(ws + 83886080ull);      // 33,554,432 B (natural [c][h][w])
    float* mH    = (float*)(ws + 117440512ull);   // 1,048,576 B
    float* sH    = (float*)(ws + 118489088ull);   // 1,048,576 B
    u16* wbf     = (u16*)(ws + 119537664ull);     // 20,480 B
    float* bias80= (float*)(ws + 119558144ull);   // 320 B
    u16* xybuf   = nullptr;                       // 33,554,432 B (optional)
    if (ws_size >= 119603200ull + 33554432ull)
        xybuf = (u16*)(ws + 119603200ull);

    k_wcvt<<<40, 256, 0, stream>>>(qw, qb, kw, kb, vw, vb, wbf, bias80);
    k_qkv_mfma<<<2048, 256, 0, stream>>>(x, y, wbf, bias80, qkv, xybuf);
    k_tr <<<5120, 256, 0, stream>>>(qkv, qkvT);          // 1280 planes
    k_col<<<2048, 512, 0, stream>>>(qkvT, colpart, mH, sH);
    k_row<<<2048, 512, 0, stream>>>(qkv, colpart, mH, sH, x, y, xybuf, gm, out);
}

// Round 11
// 180.883 us; speedup vs baseline: 1.1440x; 1.1440x over previous
//
#include <hip/hip_runtime.h>

#define NCH 80
#define HW 16384

typedef unsigned short u16;
typedef unsigned int u32;
typedef short s16x8 __attribute__((ext_vector_type(8)));
typedef float f32x4 __attribute__((ext_vector_type(4)));

__device__ __forceinline__ float b2f_lo(u32 pk){ union{u32 u; float f;} c; c.u = pk<<16; return c.f; }
__device__ __forceinline__ float b2f_hi(u32 pk){ union{u32 u; float f;} c; c.u = pk & 0xffff0000u; return c.f; }
__device__ __forceinline__ u16 f2b_hw(float f){
    union{ __bf16 h; u16 s; } c; c.h = (__bf16)f; return c.s;
}
__device__ __forceinline__ u32 pk2(float a, float b){
    return (u32)f2b_hw(a) | ((u32)f2b_hw(b)<<16);
}
#define NEG_INF (-__builtin_inff())

union U4S8 { uint4 u; s16x8 v; };

// ---------------------------------------------------------------- P0: weight pack -> bf16
__global__ __launch_bounds__(256) void k_wcvt(
    const float* __restrict__ qw, const float* __restrict__ qb,
    const float* __restrict__ kw, const float* __restrict__ kb,
    const float* __restrict__ vw, const float* __restrict__ vb,
    u16* __restrict__ wbf, float* __restrict__ bias80)
{
    int i = blockIdx.x*256 + threadIdx.x;     // 0..10239
    int ch = i >> 7, cin = i & 127;
    float v;
    if (ch < 8)       v = (cin < 64) ? qw[ch*64 + cin] : 0.f;
    else if (ch < 16) v = (cin >= 64) ? kw[(ch-8)*64 + (cin-64)] : 0.f;
    else              v = vw[(ch-16)*128 + cin];
    wbf[i] = f2b_hw(v);
    if (i < 80){
        bias80[i] = (i<8) ? qb[i] : (i<16) ? kb[i-8] : vb[i-16];
    }
}

// ---------------------------------------------------------------- P1: qkv via MFMA (R6 structure + load fence + XCD swizzle)
// Block = 256 thr (4 waves), 128 pixels. Phase A1: ALL 16 float4 loads in flight
// (sched_barrier fence stops the compiler sinking them); A2: convert -> LDS + xy emit.
// Phase B: MFMA vs L1-resident weights.
__global__ __launch_bounds__(256) void k_qkv_mfma(
    const float* __restrict__ x, const float* __restrict__ y,
    const u16* __restrict__ wbf, const float* __restrict__ bias80,
    u16* __restrict__ qkv, u16* __restrict__ xy)
{
    // a32[cp][px]: cp<32 -> x channel-pair (2cp,2cp+1); cp>=32 -> y channel-pair.
    __shared__ u32 a32[64*132];

    int t = threadIdx.x;
    // XCD-aware bijective swizzle: each XCD owns a contiguous 1/8 of pixels
    int bid = blockIdx.x;                    // 2048 blocks, 2048%8==0
    int xcd = bid & 7, n = bid >> 3;
    int p0 = (xcd * 256 + n) * 128;
    int b = p0 >> 14, rem = p0 & 16383;
    const float* xb = x + (size_t)b*64*HW + rem;
    const float* yb = y + (size_t)b*64*HW + rem;

    // ---- Phase A1: issue ALL 16 loads (no LDS dependency in between)
    float4 fx0[4], fx1[4], fy0[4], fy1[4];
    #pragma unroll
    for (int r=0;r<4;r++){
        int idx = t + r*256;              // 0..1023
        int cp = idx >> 5;                // 0..31 channel-pair
        int pxg = (idx & 31) * 4;         // pixel group base
        const float* xp = xb + (size_t)(2*cp)*HW + pxg;
        const float* yp = yb + (size_t)(2*cp)*HW + pxg;
        fx0[r] = *(const float4*)xp;
        fx1[r] = *(const float4*)(xp + HW);
        fy0[r] = *(const float4*)yp;
        fy1[r] = *(const float4*)(yp + HW);
    }
    // fence: keep all 16 loads issued above this point (stop sinking into A2)
    __builtin_amdgcn_sched_barrier(0);

    // ---- Phase A2: convert + LDS + fused xy emit
    #pragma unroll
    for (int r=0;r<4;r++){
        int idx = t + r*256;
        int cp = idx >> 5;
        int pxg = (idx & 31) * 4;
        uint4 wx, wy;
        wx.x = pk2(fx0[r].x, fx1[r].x);
        wx.y = pk2(fx0[r].y, fx1[r].y);
        wx.z = pk2(fx0[r].z, fx1[r].z);
        wx.w = pk2(fx0[r].w, fx1[r].w);
        wy.x = pk2(fy0[r].x, fy1[r].x);
        wy.y = pk2(fy0[r].y, fy1[r].y);
        wy.z = pk2(fy0[r].z, fy1[r].z);
        wy.w = pk2(fy0[r].w, fy1[r].w);
        *(uint4*)&a32[cp*132 + pxg]       = wx;
        *(uint4*)&a32[(32+cp)*132 + pxg]  = wy;
        if (xy){
            uint2 s0, s1;
            s0.x = pk2(fx0[r].x+fy0[r].x, fx0[r].y+fy0[r].y);
            s0.y = pk2(fx0[r].z+fy0[r].z, fx0[r].w+fy0[r].w);
            s1.x = pk2(fx1[r].x+fy1[r].x, fx1[r].y+fy1[r].y);
            s1.y = pk2(fx1[r].z+fy1[r].z, fx1[r].w+fy1[r].w);
            *(uint2*)&xy[(size_t)(b*64 + 2*cp)*HW + rem + pxg]     = s0;
            *(uint2*)&xy[(size_t)(b*64 + 2*cp+1)*HW + rem + pxg]   = s1;
        }
    }
    __syncthreads();

    // ---- Phase B: MFMA. Wave wv owns pixels [(2wv)*16, (2wv+2)*16), 5 n-tiles.
    int wv = t >> 6, l = t & 63;
    int lm = l & 15, lq = l >> 4;

    s16x8 af[2][4];
    #pragma unroll
    for (int m2=0;m2<2;m2++){
        int pxl = (wv*2 + m2)*16 + lm;
        #pragma unroll
        for (int ks=0;ks<4;ks++){
            int cpb = (ks&1)*16 + lq*4 + ((ks>>1)*32);
            U4S8 uu;
            uu.u = make_uint4(a32[(cpb+0)*132 + pxl], a32[(cpb+1)*132 + pxl],
                              a32[(cpb+2)*132 + pxl], a32[(cpb+3)*132 + pxl]);
            af[m2][ks] = uu.v;
        }
    }

    #pragma unroll
    for (int nt=0;nt<5;nt++){
        int ch = nt*16 + lm;
        const u16* wrow = wbf + ch*128 + lq*8;
        s16x8 b0 = *(const s16x8*)(wrow);
        s16x8 b1 = *(const s16x8*)(wrow + 32);
        s16x8 b2 = *(const s16x8*)(wrow + 64);
        s16x8 b3 = *(const s16x8*)(wrow + 96);
        f32x4 acc0 = (f32x4){0.f,0.f,0.f,0.f};
        f32x4 acc1 = (f32x4){0.f,0.f,0.f,0.f};
        acc0 = __builtin_amdgcn_mfma_f32_16x16x32_bf16(af[0][0], b0, acc0, 0,0,0);
        acc1 = __builtin_amdgcn_mfma_f32_16x16x32_bf16(af[1][0], b0, acc1, 0,0,0);
        acc0 = __builtin_amdgcn_mfma_f32_16x16x32_bf16(af[0][1], b1, acc0, 0,0,0);
        acc1 = __builtin_amdgcn_mfma_f32_16x16x32_bf16(af[1][1], b1, acc1, 0,0,0);
        acc0 = __builtin_amdgcn_mfma_f32_16x16x32_bf16(af[0][2], b2, acc0, 0,0,0);
        acc1 = __builtin_amdgcn_mfma_f32_16x16x32_bf16(af[1][2], b2, acc1, 0,0,0);
        acc0 = __builtin_amdgcn_mfma_f32_16x16x32_bf16(af[0][3], b3, acc0, 0,0,0);
        acc1 = __builtin_amdgcn_mfma_f32_16x16x32_bf16(af[1][3], b3, acc1, 0,0,0);
        float bs = bias80[ch];
        size_t chbase = (size_t)(b*NCH + ch)*HW + rem;
        uint2 st0, st1;
        st0.x = pk2(acc0[0]+bs, acc0[1]+bs);
        st0.y = pk2(acc0[2]+bs, acc0[3]+bs);
        st1.x = pk2(acc1[0]+bs, acc1[1]+bs);
        st1.y = pk2(acc1[2]+bs, acc1[3]+bs);
        *(uint2*)&qkv[chbase + (wv*2+0)*16 + lq*4] = st0;
        *(uint2*)&qkv[chbase + (wv*2+1)*16 + lq*4] = st1;
    }
}

// ------------------------------------------------ 128x128 bf16 plane transpose (unchanged)
__global__ __launch_bounds__(256) void k_tr(const u16* __restrict__ src, u16* __restrict__ dst)
{
    __shared__ u16 tile[64][65];
    int blk = blockIdx.x;
    int plane = blk >> 2, tq = blk & 3;
    int r0 = (tq >> 1) * 64, c0 = (tq & 1) * 64;
    const u16* s = src + (size_t)plane * HW;
    u16* d = dst + (size_t)plane * HW;
    int col = threadIdx.x & 63, rr = threadIdx.x >> 6;
    #pragma unroll
    for (int k=0;k<16;k++){
        int r = k*4 + rr;
        tile[r][col] = s[(r0+r)*128 + c0 + col];
    }
    __syncthreads();
    #pragma unroll
    for (int k=0;k<16;k++){
        int r = k*4 + rr;
        d[(c0+r)*128 + r0 + col] = tile[col][r];
    }
}

// ---------------------------------------------------------------- P2: column pass (MFMA PV, XCD swizzle)
__global__ __launch_bounds__(512, 4) void k_col(
    const u16* __restrict__ qkvT, u16* __restrict__ colT,
    float* __restrict__ mH, float* __restrict__ sH)
{
    __shared__ __align__(16) float q_s[8*128];    // [o][h]
    __shared__ __align__(16) float k_sw[8*128];   // [g][o^((g>>3)&7)]
    __shared__ __align__(16) u16  v_bf[64*128];   // [c][g], word ^ ((c&7)<<2)
    __shared__ __align__(16) u16  p_bf[128*128];  // [h][g], word ^ ((h&7)<<2)

    int t = threadIdx.x;
    // XCD-aware bijective swizzle: contiguous (b,w) ranges per XCD
    int bid = blockIdx.x;
    int i = (bid & 7) * 256 + (bid >> 3);   // 0..2047
    int b = i >> 7, w = i & 127;
    const u32* src = (const u32*)(qkvT + (size_t)b*NCH*HW + w*128);
    u32* v32 = (u32*)v_bf;
    u32* p32 = (u32*)p_bf;

    #pragma unroll
    for (int r=0;r<2;r++){
        int idx = t + r*512;
        int ch = idx >> 6, hp = idx & 63;
        u32 pk = src[ch*8192 + hp];
        int g0 = hp*2;
        if (ch < 8){
            *(float2*)&q_s[ch*128 + g0] = make_float2(b2f_lo(pk), b2f_hi(pk));
        } else {
            int o = ch - 8;
            k_sw[g0*8     + (o ^ ((g0>>3)&7))]     = b2f_lo(pk);
            k_sw[(g0+1)*8 + (o ^ (((g0+1)>>3)&7))] = b2f_hi(pk);
        }
    }
    #pragma unroll
    for (int r=0;r<8;r++){
        int idx = t + r*512;
        int c = idx >> 6, gp = idx & 63;
        v32[(c*64 + gp) ^ ((c&7)<<2)] = src[(16+c)*8192 + gp];
    }
    __syncthreads();

    int tr = t >> 4, tc = t & 15;
    int h0 = tr*4, g0 = tc*8;
    float e[4][8];
    #pragma unroll
    for (int i2=0;i2<4;i2++)
        #pragma unroll
        for (int j=0;j<8;j++) e[i2][j] = 0.f;

    #pragma unroll
    for (int o=0;o<8;o++){
        float qv[4], kv[8];
        #pragma unroll
        for (int i2=0;i2<4;i2++) qv[i2] = q_s[o*128 + h0 + i2];
        int kb = o ^ (tc & 7);
        #pragma unroll
        for (int j=0;j<8;j++) kv[j] = k_sw[(g0+j)*8 + kb];
        #pragma unroll
        for (int i2=0;i2<4;i2++)
            #pragma unroll
            for (int j=0;j<8;j++) e[i2][j] += qv[i2]*kv[j];
    }
    #pragma unroll
    for (int i2=0;i2<4;i2++){
        int h = h0 + i2;
        if ((h>>3) == tc) e[i2][h&7] = NEG_INF;
    }
    #pragma unroll
    for (int i2=0;i2<4;i2++){
        int h = h0 + i2;
        float m = e[i2][0];
        #pragma unroll
        for (int j=1;j<8;j++) m = fmaxf(m, e[i2][j]);
        m = fmaxf(m, __shfl_xor(m,1));
        m = fmaxf(m, __shfl_xor(m,2));
        m = fmaxf(m, __shfl_xor(m,4));
        m = fmaxf(m, __shfl_xor(m,8));
        float s = 0.f;
        #pragma unroll
        for (int j=0;j<8;j++){ float pp = __expf(e[i2][j]-m); e[i2][j]=pp; s += pp; }
        s += __shfl_xor(s,1);
        s += __shfl_xor(s,2);
        s += __shfl_xor(s,4);
        s += __shfl_xor(s,8);
        if (tc == 0){
            mH[b*HW + h*128 + w] = m;
            sH[b*HW + h*128 + w] = s;
        }
        uint4 pw;
        pw.x = pk2(e[i2][0], e[i2][1]);
        pw.y = pk2(e[i2][2], e[i2][3]);
        pw.z = pk2(e[i2][4], e[i2][5]);
        pw.w = pk2(e[i2][6], e[i2][7]);
        *(uint4*)&p32[(h*64 + tc*4) ^ ((h&7)<<2)] = pw;
    }
    __syncthreads();

    int wv = t >> 6, l = t & 63;
    int lm = l & 15, lq = l >> 4;
    int mt = wv;
    f32x4 acc[4];
    #pragma unroll
    for (int nt=0; nt<4; nt++) acc[nt] = (f32x4){0.f,0.f,0.f,0.f};

    #pragma unroll
    for (int ks=0; ks<4; ks++){
        int ri = mt*16 + lm;
        s16x8 a = *(const s16x8*)&p32[(ri*64 + ks*16 + lq*4) ^ ((ri&7)<<2)];
        #pragma unroll
        for (int nt=0; nt<4; nt++){
            int c = nt*16 + lm;
            s16x8 bf_ = *(const s16x8*)&v32[(c*64 + ks*16 + lq*4) ^ ((c&7)<<2)];
            acc[nt] = __builtin_amdgcn_mfma_f32_16x16x32_bf16(a, bf_, acc[nt], 0, 0, 0);
        }
    }
    #pragma unroll
    for (int nt=0; nt<4; nt++){
        int c = nt*16 + lm;
        int hh = mt*16 + lq*4;
        uint2 st;
        st.x = pk2(acc[nt][0], acc[nt][1]);
        st.y = pk2(acc[nt][2], acc[nt][3]);
        *(uint2*)&colT[((size_t)(b*64+c)*128 + w)*128 + hh] = st;
    }
}

// ---------------------------------------------------------------- P3: row pass + combine (MFMA PV, XCD swizzle)
__global__ __launch_bounds__(512, 4) void k_row(
    const u16* __restrict__ qkv, const u16* __restrict__ colpart,
    const float* __restrict__ mH, const float* __restrict__ sH,
    const float* __restrict__ x, const float* __restrict__ y,
    const u16* __restrict__ xy,
    const float* __restrict__ gamma_p, float* __restrict__ out)
{
    __shared__ __align__(16) float q_s[8*128];
    __shared__ __align__(16) float k_sw[8*128];
    __shared__ __align__(16) u16  v_bf[64*128];
    __shared__ __align__(16) u16  p_bf[128*128];
    __shared__ float fc_s[128], fr_s[128];

    int t = threadIdx.x;
    // XCD-aware bijective swizzle: contiguous (b,h) ranges per XCD
    int bid = blockIdx.x;
    int i = (bid & 7) * 256 + (bid >> 3);   // 0..2047
    int b = i >> 7, h = i & 127;
    const u32* src = (const u32*)(qkv + (size_t)b*NCH*HW + h*128);
    u32* v32 = (u32*)v_bf;
    u32* p32 = (u32*)p_bf;

    #pragma unroll
    for (int r=0;r<2;r++){
        int idx = t + r*512;
        int ch = idx >> 6, wp = idx & 63;
        u32 pk = src[ch*8192 + wp];
        int u0 = wp*2;
        if (ch < 8){
            *(float2*)&q_s[ch*128 + u0] = make_float2(b2f_lo(pk), b2f_hi(pk));
        } else {
            int o = ch - 8;
            k_sw[u0*8     + (o ^ ((u0>>3)&7))]     = b2f_lo(pk);
            k_sw[(u0+1)*8 + (o ^ (((u0+1)>>3)&7))] = b2f_hi(pk);
        }
    }
    #pragma unroll
    for (int r=0;r<8;r++){
        int idx = t + r*512;
        int c = idx >> 6, up = idx & 63;
        v32[(c*64 + up) ^ ((c&7)<<2)] = src[(16+c)*8192 + up];
    }
    __syncthreads();

    int tr = t >> 4, tc = t & 15;
    int w0 = tr*4, u0 = tc*8;
    float e[4][8];
    #pragma unroll
    for (int i2=0;i2<4;i2++)
        #pragma unroll
        for (int j=0;j<8;j++) e[i2][j] = 0.f;

    #pragma unroll
    for (int o=0;o<8;o++){
        float qv[4], kv[8];
        #pragma unroll
        for (int i2=0;i2<4;i2++) qv[i2] = q_s[o*128 + w0 + i2];
        int kb = o ^ (tc & 7);
        #pragma unroll
        for (int j=0;j<8;j++) kv[j] = k_sw[(u0+j)*8 + kb];
        #pragma unroll
        for (int i2=0;i2<4;i2++)
            #pragma unroll
            for (int j=0;j<8;j++) e[i2][j] += qv[i2]*kv[j];
    }
    int pixbase = b*HW + h*128;
    #pragma unroll
    for (int i2=0;i2<4;i2++){
        int wp = w0 + i2;
        float m = e[i2][0];
        #pragma unroll
        for (int j=1;j<8;j++) m = fmaxf(m, e[i2][j]);
        m = fmaxf(m, __shfl_xor(m,1));
        m = fmaxf(m, __shfl_xor(m,2));
        m = fmaxf(m, __shfl_xor(m,4));
        m = fmaxf(m, __shfl_xor(m,8));
        float mh = mH[pixbase + wp];
        float sh = sH[pixbase + wp];
        float mg = fmaxf(m, mh);
        float s = 0.f;
        #pragma unroll
        for (int j=0;j<8;j++){ float pp = __expf(e[i2][j]-mg); e[i2][j]=pp; s += pp; }
        s += __shfl_xor(s,1);
        s += __shfl_xor(s,2);
        s += __shfl_xor(s,4);
        s += __shfl_xor(s,8);
        if (tc == 0){
            float ef = __expf(mh - mg);
            float stot = sh*ef + s;
            fc_s[wp] = ef/stot;
            fr_s[wp] = 1.0f/stot;
        }
        uint4 pw;
        pw.x = pk2(e[i2][0], e[i2][1]);
        pw.y = pk2(e[i2][2], e[i2][3]);
        pw.z = pk2(e[i2][4], e[i2][5]);
        pw.w = pk2(e[i2][6], e[i2][7]);
        *(uint4*)&p32[(wp*64 + tc*4) ^ ((wp&7)<<2)] = pw;
    }
    __syncthreads();

    int wv = t >> 6, l = t & 63;
    int lm = l & 15, lq = l >> 4;
    int mt = wv;
    f32x4 acc[4];
    #pragma unroll
    for (int nt=0; nt<4; nt++) acc[nt] = (f32x4){0.f,0.f,0.f,0.f};

    #pragma unroll
    for (int ks=0; ks<4; ks++){
        int ri = mt*16 + lm;
        s16x8 a = *(const s16x8*)&p32[(ri*64 + ks*16 + lq*4) ^ ((ri&7)<<2)];
        #pragma unroll
        for (int nt=0; nt<4; nt++){
            int c = nt*16 + lm;
            s16x8 bf_ = *(const s16x8*)&v32[(c*64 + ks*16 + lq*4) ^ ((c&7)<<2)];
            acc[nt] = __builtin_amdgcn_mfma_f32_16x16x32_bf16(a, bf_, acc[nt], 0, 0, 0);
        }
    }
    float gm = gamma_p[0];
    int wq0 = mt*16 + lq*4;
    float fcv[4], frv[4];
    #pragma unroll
    for (int r2=0;r2<4;r2++){ fcv[r2] = fc_s[wq0+r2]; frv[r2] = fr_s[wq0+r2]; }

    #pragma unroll
    for (int nt=0; nt<4; nt++){
        int c = nt*16 + lm;
        size_t off = ((size_t)(b*64+c)*128 + h)*128 + wq0;
        uint2 cpv = *(const uint2*)&colpart[off];
        float cp[4] = {b2f_lo(cpv.x), b2f_hi(cpv.x), b2f_lo(cpv.y), b2f_hi(cpv.y)};
        float xs[4];
        if (xy){
            uint2 xv = *(const uint2*)&xy[off];
            xs[0]=b2f_lo(xv.x); xs[1]=b2f_hi(xv.x); xs[2]=b2f_lo(xv.y); xs[3]=b2f_hi(xv.y);
        } else {
            float4 x4 = *(const float4*)&x[off];
            float4 y4 = *(const float4*)&y[off];
            xs[0]=x4.x+y4.x; xs[1]=x4.y+y4.y; xs[2]=x4.z+y4.z; xs[3]=x4.w+y4.w;
        }
        float4 o4;
        o4.x = gm*(cp[0]*fcv[0] + acc[nt][0]*frv[0]) + xs[0];
        o4.y = gm*(cp[1]*fcv[1] + acc[nt][1]*frv[1]) + xs[1];
        o4.z = gm*(cp[2]*fcv[2] + acc[nt][2]*frv[2]) + xs[2];
        o4.w = gm*(cp[3]*fcv[3] + acc[nt][3]*frv[3]) + xs[3];
        *(float4*)&out[off] = o4;
    }
}

// ----------------------------------------------------------------
extern "C" void kernel_launch(void* const* d_in, const int* in_sizes, int n_in,
                              void* d_out, int out_size, void* d_ws, size_t ws_size,
                              hipStream_t stream)
{
    (void)in_sizes; (void)n_in; (void)out_size;
    const float* x  = (const float*)d_in[0];
    const float* y  = (const float*)d_in[1];
    const float* qw = (const float*)d_in[2];
    const float* qb = (const float*)d_in[3];
    const float* kw = (const float*)d_in[4];
    const float* kb = (const float*)d_in[5];
    const float* vw = (const float*)d_in[6];
    const float* vb = (const float*)d_in[7];
    const float* gm = (const float*)d_in[8];
    float* out = (float*)d_out;

    char* ws = (char*)d_ws;
    u16* qkv     = (u16*)(ws);                    // 41,943,040 B
    u16* qkvT    = (u16*)(ws + 41943040ull);      // 41,943,040 B
    u16* colT    = (u16*)(ws + 83886080ull);      // 33,554,432 B
    u16* colpart = qkvT;                          // alias: qkvT dead after k_col
    float* mH    = (float*)(ws + 117440512ull);   // 1,048,576 B
    float* sH    = (float*)(ws + 118489088ull);   // 1,048,576 B
    u16* wbf     = (u16*)(ws + 119537664ull);     // 20,480 B
    float* bias80= (float*)(ws + 119558144ull);   // 320 B
    u16* xybuf   = nullptr;                       // 33,554,432 B (optional)
    if (ws_size >= 119603200ull + 33554432ull)
        xybuf = (u16*)(ws + 119603200ull);

    k_wcvt<<<40, 256, 0, stream>>>(qw, qb, kw, kb, vw, vb, wbf, bias80);
    k_qkv_mfma<<<2048, 256, 0, stream>>>(x, y, wbf, bias80, qkv, xybuf);
    k_tr <<<5120, 256, 0, stream>>>(qkv, qkvT);          // 1280 planes
    k_col<<<2048, 512, 0, stream>>>(qkvT, colT, mH, sH);
    k_tr <<<4096, 256, 0, stream>>>(colT, colpart);      // 1024 planes
    k_row<<<2048, 512, 0, stream>>>(qkv, colpart, mH, sH, x, y, xybuf, gm, out);
}

// Round 12
// 165.137 us; speedup vs baseline: 1.2531x; 1.0954x over previous
//
#include <hip/hip_runtime.h>

#define NCH 80
#define HW 16384

typedef unsigned short u16;
typedef unsigned int u32;
typedef short s16x8 __attribute__((ext_vector_type(8)));
typedef float f32x4 __attribute__((ext_vector_type(4)));

__device__ __forceinline__ float b2f_lo(u32 pk){ union{u32 u; float f;} c; c.u = pk<<16; return c.f; }
__device__ __forceinline__ float b2f_hi(u32 pk){ union{u32 u; float f;} c; c.u = pk & 0xffff0000u; return c.f; }
__device__ __forceinline__ u16 f2b_hw(float f){
    union{ __bf16 h; u16 s; } c; c.h = (__bf16)f; return c.s;
}
__device__ __forceinline__ u32 pk2(float a, float b){
    return (u32)f2b_hw(a) | ((u32)f2b_hw(b)<<16);
}
#define NEG_INF (-__builtin_inff())

union U4S8 { uint4 u; s16x8 v; };

// ---------------------------------------------------------------- P0: weight pack -> bf16
__global__ __launch_bounds__(256) void k_wcvt(
    const float* __restrict__ qw, const float* __restrict__ qb,
    const float* __restrict__ kw, const float* __restrict__ kb,
    const float* __restrict__ vw, const float* __restrict__ vb,
    u16* __restrict__ wbf, float* __restrict__ bias80)
{
    int i = blockIdx.x*256 + threadIdx.x;     // 0..10239
    int ch = i >> 7, cin = i & 127;
    float v;
    if (ch < 8)       v = (cin < 64) ? qw[ch*64 + cin] : 0.f;
    else if (ch < 16) v = (cin >= 64) ? kw[(ch-8)*64 + (cin-64)] : 0.f;
    else              v = vw[(ch-16)*128 + cin];
    wbf[i] = f2b_hw(v);
    if (i < 80){
        bias80[i] = (i<8) ? qb[i] : (i<16) ? kb[i-8] : vb[i-16];
    }
}

// ---------------------------------------------------------------- P1: qkv via MFMA (R6 structure, best measured: 69us)
// Block = 256 thr (4 waves), 128 pixels. Phase A: 16 float4 loads, then
// convert -> LDS [cp][px] + fused xy emit. Phase B: MFMA vs L1-resident weights.
__global__ __launch_bounds__(256) void k_qkv_mfma(
    const float* __restrict__ x, const float* __restrict__ y,
    const u16* __restrict__ wbf, const float* __restrict__ bias80,
    u16* __restrict__ qkv, u16* __restrict__ xy)
{
    // a32[cp][px]: cp<32 -> x channel-pair (2cp,2cp+1); cp>=32 -> y channel-pair.
    __shared__ u32 a32[64*132];

    int t = threadIdx.x;
    int p0 = blockIdx.x * 128;
    int b = p0 >> 14, rem = p0 & 16383;
    const float* xb = x + (size_t)b*64*HW + rem;
    const float* yb = y + (size_t)b*64*HW + rem;

    // ---- Phase A1: issue ALL 16 loads (no LDS dependency in between)
    float4 fx0[4], fx1[4], fy0[4], fy1[4];
    #pragma unroll
    for (int r=0;r<4;r++){
        int idx = t + r*256;              // 0..1023
        int cp = idx >> 5;                // 0..31 channel-pair
        int pxg = (idx & 31) * 4;         // pixel group base
        const float* xp = xb + (size_t)(2*cp)*HW + pxg;
        const float* yp = yb + (size_t)(2*cp)*HW + pxg;
        fx0[r] = *(const float4*)xp;
        fx1[r] = *(const float4*)(xp + HW);
        fy0[r] = *(const float4*)yp;
        fy1[r] = *(const float4*)(yp + HW);
    }
    // ---- Phase A2: convert + LDS + fused xy emit
    #pragma unroll
    for (int r=0;r<4;r++){
        int idx = t + r*256;
        int cp = idx >> 5;
        int pxg = (idx & 31) * 4;
        uint4 wx, wy;
        wx.x = pk2(fx0[r].x, fx1[r].x);
        wx.y = pk2(fx0[r].y, fx1[r].y);
        wx.z = pk2(fx0[r].z, fx1[r].z);
        wx.w = pk2(fx0[r].w, fx1[r].w);
        wy.x = pk2(fy0[r].x, fy1[r].x);
        wy.y = pk2(fy0[r].y, fy1[r].y);
        wy.z = pk2(fy0[r].z, fy1[r].z);
        wy.w = pk2(fy0[r].w, fy1[r].w);
        *(uint4*)&a32[cp*132 + pxg]       = wx;
        *(uint4*)&a32[(32+cp)*132 + pxg]  = wy;
        if (xy){
            uint2 s0, s1;
            s0.x = pk2(fx0[r].x+fy0[r].x, fx0[r].y+fy0[r].y);
            s0.y = pk2(fx0[r].z+fy0[r].z, fx0[r].w+fy0[r].w);
            s1.x = pk2(fx1[r].x+fy1[r].x, fx1[r].y+fy1[r].y);
            s1.y = pk2(fx1[r].z+fy1[r].z, fx1[r].w+fy1[r].w);
            *(uint2*)&xy[(size_t)(b*64 + 2*cp)*HW + rem + pxg]     = s0;
            *(uint2*)&xy[(size_t)(b*64 + 2*cp+1)*HW + rem + pxg]   = s1;
        }
    }
    __syncthreads();

    // ---- Phase B: MFMA. Wave wv owns pixels [(2wv)*16, (2wv+2)*16), 5 n-tiles.
    int wv = t >> 6, l = t & 63;
    int lm = l & 15, lq = l >> 4;

    s16x8 af[2][4];
    #pragma unroll
    for (int m2=0;m2<2;m2++){
        int pxl = (wv*2 + m2)*16 + lm;
        #pragma unroll
        for (int ks=0;ks<4;ks++){
            int cpb = (ks&1)*16 + lq*4 + ((ks>>1)*32);
            U4S8 uu;
            uu.u = make_uint4(a32[(cpb+0)*132 + pxl], a32[(cpb+1)*132 + pxl],
                              a32[(cpb+2)*132 + pxl], a32[(cpb+3)*132 + pxl]);
            af[m2][ks] = uu.v;
        }
    }

    #pragma unroll
    for (int nt=0;nt<5;nt++){
        int ch = nt*16 + lm;
        const u16* wrow = wbf + ch*128 + lq*8;
        s16x8 b0 = *(const s16x8*)(wrow);
        s16x8 b1 = *(const s16x8*)(wrow + 32);
        s16x8 b2 = *(const s16x8*)(wrow + 64);
        s16x8 b3 = *(const s16x8*)(wrow + 96);
        f32x4 acc0 = (f32x4){0.f,0.f,0.f,0.f};
        f32x4 acc1 = (f32x4){0.f,0.f,0.f,0.f};
        acc0 = __builtin_amdgcn_mfma_f32_16x16x32_bf16(af[0][0], b0, acc0, 0,0,0);
        acc1 = __builtin_amdgcn_mfma_f32_16x16x32_bf16(af[1][0], b0, acc1, 0,0,0);
        acc0 = __builtin_amdgcn_mfma_f32_16x16x32_bf16(af[0][1], b1, acc0, 0,0,0);
        acc1 = __builtin_amdgcn_mfma_f32_16x16x32_bf16(af[1][1], b1, acc1, 0,0,0);
        acc0 = __builtin_amdgcn_mfma_f32_16x16x32_bf16(af[0][2], b2, acc0, 0,0,0);
        acc1 = __builtin_amdgcn_mfma_f32_16x16x32_bf16(af[1][2], b2, acc1, 0,0,0);
        acc0 = __builtin_amdgcn_mfma_f32_16x16x32_bf16(af[0][3], b3, acc0, 0,0,0);
        acc1 = __builtin_amdgcn_mfma_f32_16x16x32_bf16(af[1][3], b3, acc1, 0,0,0);
        float bs = bias80[ch];
        size_t chbase = (size_t)(b*NCH + ch)*HW + rem;
        uint2 st0, st1;
        st0.x = pk2(acc0[0]+bs, acc0[1]+bs);
        st0.y = pk2(acc0[2]+bs, acc0[3]+bs);
        st1.x = pk2(acc1[0]+bs, acc1[1]+bs);
        st1.y = pk2(acc1[2]+bs, acc1[3]+bs);
        *(uint2*)&qkv[chbase + (wv*2+0)*16 + lq*4] = st0;
        *(uint2*)&qkv[chbase + (wv*2+1)*16 + lq*4] = st1;
    }
}

// ------------------------------------------------ 128x128 bf16 plane transpose (unchanged)
__global__ __launch_bounds__(256) void k_tr(const u16* __restrict__ src, u16* __restrict__ dst)
{
    __shared__ u16 tile[64][65];
    int blk = blockIdx.x;
    int plane = blk >> 2, tq = blk & 3;
    int r0 = (tq >> 1) * 64, c0 = (tq & 1) * 64;
    const u16* s = src + (size_t)plane * HW;
    u16* d = dst + (size_t)plane * HW;
    int col = threadIdx.x & 63, rr = threadIdx.x >> 6;
    #pragma unroll
    for (int k=0;k<16;k++){
        int r = k*4 + rr;
        tile[r][col] = s[(r0+r)*128 + c0 + col];
    }
    __syncthreads();
    #pragma unroll
    for (int k=0;k<16;k++){
        int r = k*4 + rr;
        d[(c0+r)*128 + r0 + col] = tile[col][r];
    }
}

// ---------------------------------------------------------------- P2: column pass (MFMA PV)
__global__ __launch_bounds__(512, 4) void k_col(
    const u16* __restrict__ qkvT, u16* __restrict__ colT,
    float* __restrict__ mH, float* __restrict__ sH)
{
    __shared__ __align__(16) float q_s[8*128];    // [o][h]
    __shared__ __align__(16) float k_sw[8*128];   // [g][o^((g>>3)&7)]
    __shared__ __align__(16) u16  v_bf[64*128];   // [c][g], word ^ ((c&7)<<2)
    __shared__ __align__(16) u16  p_bf[128*128];  // [h][g], word ^ ((h&7)<<2)

    int t = threadIdx.x;
    int b = blockIdx.x >> 7, w = blockIdx.x & 127;
    const u32* src = (const u32*)(qkvT + (size_t)b*NCH*HW + w*128);
    u32* v32 = (u32*)v_bf;
    u32* p32 = (u32*)p_bf;

    #pragma unroll
    for (int r=0;r<2;r++){
        int idx = t + r*512;
        int ch = idx >> 6, hp = idx & 63;
        u32 pk = src[ch*8192 + hp];
        int g0 = hp*2;
        if (ch < 8){
            *(float2*)&q_s[ch*128 + g0] = make_float2(b2f_lo(pk), b2f_hi(pk));
        } else {
            int o = ch - 8;
            k_sw[g0*8     + (o ^ ((g0>>3)&7))]     = b2f_lo(pk);
            k_sw[(g0+1)*8 + (o ^ (((g0+1)>>3)&7))] = b2f_hi(pk);
        }
    }
    #pragma unroll
    for (int r=0;r<8;r++){
        int idx = t + r*512;
        int c = idx >> 6, gp = idx & 63;
        v32[(c*64 + gp) ^ ((c&7)<<2)] = src[(16+c)*8192 + gp];
    }
    __syncthreads();

    int tr = t >> 4, tc = t & 15;
    int h0 = tr*4, g0 = tc*8;
    float e[4][8];
    #pragma unroll
    for (int i=0;i<4;i++)
        #pragma unroll
        for (int j=0;j<8;j++) e[i][j] = 0.f;

    #pragma unroll
    for (int o=0;o<8;o++){
        float qv[4], kv[8];
        #pragma unroll
        for (int i=0;i<4;i++) qv[i] = q_s[o*128 + h0 + i];
        int kb = o ^ (tc & 7);
        #pragma unroll
        for (int j=0;j<8;j++) kv[j] = k_sw[(g0+j)*8 + kb];
        #pragma unroll
        for (int i=0;i<4;i++)
            #pragma unroll
            for (int j=0;j<8;j++) e[i][j] += qv[i]*kv[j];
    }
    #pragma unroll
    for (int i=0;i<4;i++){
        int h = h0 + i;
        if ((h>>3) == tc) e[i][h&7] = NEG_INF;
    }
    #pragma unroll
    for (int i=0;i<4;i++){
        int h = h0 + i;
        float m = e[i][0];
        #pragma unroll
        for (int j=1;j<8;j++) m = fmaxf(m, e[i][j]);
        m = fmaxf(m, __shfl_xor(m,1));
        m = fmaxf(m, __shfl_xor(m,2));
        m = fmaxf(m, __shfl_xor(m,4));
        m = fmaxf(m, __shfl_xor(m,8));
        float s = 0.f;
        #pragma unroll
        for (int j=0;j<8;j++){ float pp = __expf(e[i][j]-m); e[i][j]=pp; s += pp; }
        s += __shfl_xor(s,1);
        s += __shfl_xor(s,2);
        s += __shfl_xor(s,4);
        s += __shfl_xor(s,8);
        if (tc == 0){
            mH[b*HW + h*128 + w] = m;
            sH[b*HW + h*128 + w] = s;
        }
        uint4 pw;
        pw.x = pk2(e[i][0], e[i][1]);
        pw.y = pk2(e[i][2], e[i][3]);
        pw.z = pk2(e[i][4], e[i][5]);
        pw.w = pk2(e[i][6], e[i][7]);
        *(uint4*)&p32[(h*64 + tc*4) ^ ((h&7)<<2)] = pw;
    }
    __syncthreads();

    int wv = t >> 6, l = t & 63;
    int lm = l & 15, lq = l >> 4;
    int mt = wv;
    f32x4 acc[4];
    #pragma unroll
    for (int nt=0; nt<4; nt++) acc[nt] = (f32x4){0.f,0.f,0.f,0.f};

    #pragma unroll
    for (int ks=0; ks<4; ks++){
        int ri = mt*16 + lm;
        s16x8 a = *(const s16x8*)&p32[(ri*64 + ks*16 + lq*4) ^ ((ri&7)<<2)];
        #pragma unroll
        for (int nt=0; nt<4; nt++){
            int c = nt*16 + lm;
            s16x8 bf_ = *(const s16x8*)&v32[(c*64 + ks*16 + lq*4) ^ ((c&7)<<2)];
            acc[nt] = __builtin_amdgcn_mfma_f32_16x16x32_bf16(a, bf_, acc[nt], 0, 0, 0);
        }
    }
    #pragma unroll
    for (int nt=0; nt<4; nt++){
        int c = nt*16 + lm;
        int hh = mt*16 + lq*4;
        uint2 st;
        st.x = pk2(acc[nt][0], acc[nt][1]);
        st.y = pk2(acc[nt][2], acc[nt][3]);
        *(uint2*)&colT[((size_t)(b*64+c)*128 + w)*128 + hh] = st;
    }
}

// ---------------------------------------------------------------- P3: row pass + combine (MFMA PV)
__global__ __launch_bounds__(512, 4) void k_row(
    const u16* __restrict__ qkv, const u16* __restrict__ colpart,
    const float* __restrict__ mH, const float* __restrict__ sH,
    const float* __restrict__ x, const float* __restrict__ y,
    const u16* __restrict__ xy,
    const float* __restrict__ gamma_p, float* __restrict__ out)
{
    __shared__ __align__(16) float q_s[8*128];
    __shared__ __align__(16) float k_sw[8*128];
    __shared__ __align__(16) u16  v_bf[64*128];
    __shared__ __align__(16) u16  p_bf[128*128];
    __shared__ float fc_s[128], fr_s[128];

    int t = threadIdx.x;
    int b = blockIdx.x >> 7, h = blockIdx.x & 127;
    const u32* src = (const u32*)(qkv + (size_t)b*NCH*HW + h*128);
    u32* v32 = (u32*)v_bf;
    u32* p32 = (u32*)p_bf;

    #pragma unroll
    for (int r=0;r<2;r++){
        int idx = t + r*512;
        int ch = idx >> 6, wp = idx & 63;
        u32 pk = src[ch*8192 + wp];
        int u0 = wp*2;
        if (ch < 8){
            *(float2*)&q_s[ch*128 + u0] = make_float2(b2f_lo(pk), b2f_hi(pk));
        } else {
            int o = ch - 8;
            k_sw[u0*8     + (o ^ ((u0>>3)&7))]     = b2f_lo(pk);
            k_sw[(u0+1)*8 + (o ^ (((u0+1)>>3)&7))] = b2f_hi(pk);
        }
    }
    #pragma unroll
    for (int r=0;r<8;r++){
        int idx = t + r*512;
        int c = idx >> 6, up = idx & 63;
        v32[(c*64 + up) ^ ((c&7)<<2)] = src[(16+c)*8192 + up];
    }
    __syncthreads();

    int tr = t >> 4, tc = t & 15;
    int w0 = tr*4, u0 = tc*8;
    float e[4][8];
    #pragma unroll
    for (int i=0;i<4;i++)
        #pragma unroll
        for (int j=0;j<8;j++) e[i][j] = 0.f;

    #pragma unroll
    for (int o=0;o<8;o++){
        float qv[4], kv[8];
        #pragma unroll
        for (int i=0;i<4;i++) qv[i] = q_s[o*128 + w0 + i];
        int kb = o ^ (tc & 7);
        #pragma unroll
        for (int j=0;j<8;j++) kv[j] = k_sw[(u0+j)*8 + kb];
        #pragma unroll
        for (int i=0;i<4;i++)
            #pragma unroll
            for (int j=0;j<8;j++) e[i][j] += qv[i]*kv[j];
    }
    int pixbase = b*HW + h*128;
    #pragma unroll
    for (int i=0;i<4;i++){
        int wp = w0 + i;
        float m = e[i][0];
        #pragma unroll
        for (int j=1;j<8;j++) m = fmaxf(m, e[i][j]);
        m = fmaxf(m, __shfl_xor(m,1));
        m = fmaxf(m, __shfl_xor(m,2));
        m = fmaxf(m, __shfl_xor(m,4));
        m = fmaxf(m, __shfl_xor(m,8));
        float mh = mH[pixbase + wp];
        float sh = sH[pixbase + wp];
        float mg = fmaxf(m, mh);
        float s = 0.f;
        #pragma unroll
        for (int j=0;j<8;j++){ float pp = __expf(e[i][j]-mg); e[i][j]=pp; s += pp; }
        s += __shfl_xor(s,1);
        s += __shfl_xor(s,2);
        s += __shfl_xor(s,4);
        s += __shfl_xor(s,8);
        if (tc == 0){
            float ef = __expf(mh - mg);
            float stot = sh*ef + s;
            fc_s[wp] = ef/stot;
            fr_s[wp] = 1.0f/stot;
        }
        uint4 pw;
        pw.x = pk2(e[i][0], e[i][1]);
        pw.y = pk2(e[i][2], e[i][3]);
        pw.z = pk2(e[i][4], e[i][5]);
        pw.w = pk2(e[i][6], e[i][7]);
        *(uint4*)&p32[(wp*64 + tc*4) ^ ((wp&7)<<2)] = pw;
    }
    __syncthreads();

    int wv = t >> 6, l = t & 63;
    int lm = l & 15, lq = l >> 4;
    int mt = wv;
    f32x4 acc[4];
    #pragma unroll
    for (int nt=0; nt<4; nt++) acc[nt] = (f32x4){0.f,0.f,0.f,0.f};

    #pragma unroll
    for (int ks=0; ks<4; ks++){
        int ri = mt*16 + lm;
        s16x8 a = *(const s16x8*)&p32[(ri*64 + ks*16 + lq*4) ^ ((ri&7)<<2)];
        #pragma unroll
        for (int nt=0; nt<4; nt++){
            int c = nt*16 + lm;
            s16x8 bf_ = *(const s16x8*)&v32[(c*64 + ks*16 + lq*4) ^ ((c&7)<<2)];
            acc[nt] = __builtin_amdgcn_mfma_f32_16x16x32_bf16(a, bf_, acc[nt], 0, 0, 0);
        }
    }
    float gm = gamma_p[0];
    int wq0 = mt*16 + lq*4;
    float fcv[4], frv[4];
    #pragma unroll
    for (int r2=0;r2<4;r2++){ fcv[r2] = fc_s[wq0+r2]; frv[r2] = fr_s[wq0+r2]; }

    #pragma unroll
    for (int nt=0; nt<4; nt++){
        int c = nt*16 + lm;
        size_t off = ((size_t)(b*64+c)*128 + h)*128 + wq0;
        uint2 cpv = *(const uint2*)&colpart[off];
        float cp[4] = {b2f_lo(cpv.x), b2f_hi(cpv.x), b2f_lo(cpv.y), b2f_hi(cpv.y)};
        float xs[4];
        if (xy){
            uint2 xv = *(const uint2*)&xy[off];
            xs[0]=b2f_lo(xv.x); xs[1]=b2f_hi(xv.x); xs[2]=b2f_lo(xv.y); xs[3]=b2f_hi(xv.y);
        } else {
            float4 x4 = *(const float4*)&x[off];
            float4 y4 = *(const float4*)&y[off];
            xs[0]=x4.x+y4.x; xs[1]=x4.y+y4.y; xs[2]=x4.z+y4.z; xs[3]=x4.w+y4.w;
        }
        float4 o4;
        o4.x = gm*(cp[0]*fcv[0] + acc[nt][0]*frv[0]) + xs[0];
        o4.y = gm*(cp[1]*fcv[1] + acc[nt][1]*frv[1]) + xs[1];
        o4.z = gm*(cp[2]*fcv[2] + acc[nt][2]*frv[2]) + xs[2];
        o4.w = gm*(cp[3]*fcv[3] + acc[nt][3]*frv[3]) + xs[3];
        *(float4*)&out[off] = o4;
    }
}

// ----------------------------------------------------------------
extern "C" void kernel_launch(void* const* d_in, const int* in_sizes, int n_in,
                              void* d_out, int out_size, void* d_ws, size_t ws_size,
                              hipStream_t stream)
{
    (void)in_sizes; (void)n_in; (void)out_size;
    const float* x  = (const float*)d_in[0];
    const float* y  = (const float*)d_in[1];
    const float* qw = (const float*)d_in[2];
    const float* qb = (const float*)d_in[3];
    const float* kw = (const float*)d_in[4];
    const float* kb = (const float*)d_in[5];
    const float* vw = (const float*)d_in[6];
    const float* vb = (const float*)d_in[7];
    const float* gm = (const float*)d_in[8];
    float* out = (float*)d_out;

    char* ws = (char*)d_ws;
    u16* qkv     = (u16*)(ws);                    // 41,943,040 B
    u16* qkvT    = (u16*)(ws + 41943040ull);      // 41,943,040 B
    u16* colT    = (u16*)(ws + 83886080ull);      // 33,554,432 B
    u16* colpart = qkvT;                          // alias: qkvT dead after k_col
    float* mH    = (float*)(ws + 117440512ull);   // 1,048,576 B
    float* sH    = (float*)(ws + 118489088ull);   // 1,048,576 B
    u16* wbf     = (u16*)(ws + 119537664ull);     // 20,480 B
    float* bias80= (float*)(ws + 119558144ull);   // 320 B
    u16* xybuf   = nullptr;                       // 33,554,432 B (optional)
    if (ws_size >= 119603200ull + 33554432ull)
        xybuf = (u16*)(ws + 119603200ull);

    k_wcvt<<<40, 256, 0, stream>>>(qw, qb, kw, kb, vw, vb, wbf, bias80);
    k_qkv_mfma<<<2048, 256, 0, stream>>>(x, y, wbf, bias80, qkv, xybuf);
    k_tr <<<5120, 256, 0, stream>>>(qkv, qkvT);          // 1280 planes
    k_col<<<2048, 512, 0, stream>>>(qkvT, colT, mH, sH);
    k_tr <<<4096, 256, 0, stream>>>(colT, colpart);      // 1024 planes
    k_row<<<2048, 512, 0, stream>>>(qkv, colpart, mH, sH, x, y, xybuf, gm, out);
}